// Round 2
// baseline (32111.356 us; speedup 1.0000x reference)
//
#include <hip/hip_runtime.h>
#include <hip/hip_bf16.h>

// SpatialLSTM: B=64, T=2048, D=128, H=256 (4H=1024 gates)
// One persistent block per batch row (recurrence is independent per batch).
// All math f32; OUTPUT IS FLOAT32 (reference output dtype; R1 failed because
// we stored bf16 into the f32 buffer).
#define BB 64
#define TT 2048
#define DD 128
#define HH 256
#define G4 1024
#define TC 16   // time chunk for inline X@W staging

__device__ __forceinline__ float sigf(float x) {
    return 1.0f / (1.0f + __expf(-x));
}
__device__ __forceinline__ float tanh_fast(float x) {
    // 1 - 2/(e^{2x}+1): stable at both tails (inf -> 1, -inf -> -1)
    return 1.0f - 2.0f / (__expf(2.0f * x) + 1.0f);
}

extern "C" __global__ void __launch_bounds__(512)
lstm_persist(const float* __restrict__ X, const float* __restrict__ W,
             const float* __restrict__ U, const float* __restrict__ bias,
             const float* __restrict__ h0, const float* __restrict__ c0,
             float* __restrict__ out)
{
    __shared__ float xw[TC][G4];   // 64 KB: chunk's input projection
    __shared__ float Xs[TC][DD];   // 8 KB: staged X chunk
    __shared__ float hsh[HH];      // 1 KB: current hidden state
    __shared__ float gv[G4];       // 4 KB: gate pre-activations

    const int b = blockIdx.x;
    const int tid = threadIdx.x;   // 0..511; owns gate columns 2*tid, 2*tid+1
    const float2* __restrict__ U2 = reinterpret_cast<const float2*>(U);
    const float2* __restrict__ W2 = reinterpret_cast<const float2*>(W);

    float c_reg = 0.0f;
    if (tid < HH) {
        hsh[tid] = h0[b * HH + tid];
        c_reg = c0[b * HH + tid];
    }
    const float2 bs = reinterpret_cast<const float2*>(bias)[tid];
    __syncthreads();

    for (int chunk = 0; chunk < TT / TC; ++chunk) {
        const int t0 = chunk * TC;

        // ---- stage X[b, t0:t0+TC, :] into LDS (coalesced float4) ----
        {
            const float4* src = reinterpret_cast<const float4*>(X + ((size_t)b * TT + t0) * DD);
            float4* dst = reinterpret_cast<float4*>(&Xs[0][0]);
            for (int i = tid; i < TC * DD / 4; i += 512) dst[i] = src[i];
        }
        __syncthreads();

        // ---- xw[t][j] = X_chunk @ W + bias, thread owns cols {2tid,2tid+1} ----
        float acc0[TC], acc1[TC];
        #pragma unroll
        for (int t = 0; t < TC; ++t) { acc0[t] = bs.x; acc1[t] = bs.y; }
        for (int kk = 0; kk < DD; kk += 4) {
            const float2 w0 = W2[(size_t)(kk + 0) * (G4 / 2) + tid];
            const float2 w1 = W2[(size_t)(kk + 1) * (G4 / 2) + tid];
            const float2 w2 = W2[(size_t)(kk + 2) * (G4 / 2) + tid];
            const float2 w3 = W2[(size_t)(kk + 3) * (G4 / 2) + tid];
            #pragma unroll
            for (int t = 0; t < TC; ++t) {
                const float4 xv = *reinterpret_cast<const float4*>(&Xs[t][kk]);
                acc0[t] = fmaf(xv.x, w0.x, acc0[t]); acc1[t] = fmaf(xv.x, w0.y, acc1[t]);
                acc0[t] = fmaf(xv.y, w1.x, acc0[t]); acc1[t] = fmaf(xv.y, w1.y, acc1[t]);
                acc0[t] = fmaf(xv.z, w2.x, acc0[t]); acc1[t] = fmaf(xv.z, w2.y, acc1[t]);
                acc0[t] = fmaf(xv.w, w3.x, acc0[t]); acc1[t] = fmaf(xv.w, w3.y, acc1[t]);
            }
        }
        #pragma unroll
        for (int t = 0; t < TC; ++t) {
            *reinterpret_cast<float2*>(&xw[t][2 * tid]) = make_float2(acc0[t], acc1[t]);
        }
        __syncthreads();

        // ---- TC recurrent steps ----
        for (int t = 0; t < TC; ++t) {
            const float2 x2 = *reinterpret_cast<const float2*>(&xw[t][2 * tid]);
            float a0 = x2.x, a1 = x2.y;
            #pragma unroll 4
            for (int k = 0; k < HH; k += 4) {
                const float4 hk = *reinterpret_cast<const float4*>(&hsh[k]);  // LDS broadcast
                const float2 u0 = U2[(size_t)(k + 0) * (G4 / 2) + tid];
                const float2 u1 = U2[(size_t)(k + 1) * (G4 / 2) + tid];
                const float2 u2 = U2[(size_t)(k + 2) * (G4 / 2) + tid];
                const float2 u3 = U2[(size_t)(k + 3) * (G4 / 2) + tid];
                a0 = fmaf(hk.x, u0.x, a0); a1 = fmaf(hk.x, u0.y, a1);
                a0 = fmaf(hk.y, u1.x, a0); a1 = fmaf(hk.y, u1.y, a1);
                a0 = fmaf(hk.z, u2.x, a0); a1 = fmaf(hk.z, u2.y, a1);
                a0 = fmaf(hk.w, u3.x, a0); a1 = fmaf(hk.w, u3.y, a1);
            }
            *reinterpret_cast<float2*>(&gv[2 * tid]) = make_float2(a0, a1);
            __syncthreads();
            if (tid < HH) {
                const float it = sigf(gv[tid]);
                const float ft = sigf(gv[tid + HH]);
                const float gt = tanh_fast(gv[tid + 2 * HH]);
                const float ot = sigf(gv[tid + 3 * HH]);
                c_reg = fmaf(ft, c_reg, it * gt);
                const float hn = ot * tanh_fast(c_reg);
                hsh[tid] = hn;
                out[((size_t)b * TT + (t0 + t)) * HH + tid] = hn;
            }
            __syncthreads();
        }
    }

    // final (h_t, c_t) after hidden_seq
    if (tid < HH) {
        const size_t base = (size_t)BB * TT * HH;
        out[base + (size_t)b * HH + tid] = hsh[tid];
        out[base + (size_t)BB * HH + (size_t)b * HH + tid] = c_reg;
    }
}

extern "C" void kernel_launch(void* const* d_in, const int* in_sizes, int n_in,
                              void* d_out, int out_size, void* d_ws, size_t ws_size,
                              hipStream_t stream) {
    const float* X    = (const float*)d_in[0];
    const float* W    = (const float*)d_in[1];
    const float* U    = (const float*)d_in[2];
    const float* bias = (const float*)d_in[3];
    const float* h0   = (const float*)d_in[4];
    const float* c0   = (const float*)d_in[5];
    float* out = (float*)d_out;
    (void)in_sizes; (void)n_in; (void)d_ws; (void)ws_size; (void)out_size;

    lstm_persist<<<dim3(BB), dim3(512), 0, stream>>>(X, W, U, bias, h0, c0, out);
}

// Round 3
// 13650.261 us; speedup vs baseline: 2.3524x; 2.3524x over previous
//
#include <hip/hip_runtime.h>
#include <hip/hip_bf16.h>

// SpatialLSTM: B=64, T=2048, D=128, H=256 (4H=1024)
// R3: one persistent block per batch row; U/W packed to f16 in d_ws once per
// launch; recurrence streams f16 U from L2 with v_dot2_f32_f16 (half bytes of
// f32) and 16 waves/block (K-split) for latency hiding. Output f32.
#define BB 64
#define TT 2048
#define DD 128
#define HH 256
#define G4 1024
#define TC 16

typedef _Float16 half2_t __attribute__((ext_vector_type(2)));

#if __has_builtin(__builtin_amdgcn_fdot2)
#define FDOT2(a, b, c) __builtin_amdgcn_fdot2((a), (b), (c), false)
#else
__device__ __forceinline__ float FDOT2(half2_t a, half2_t b, float c) {
    return c + (float)a[0] * (float)b[0] + (float)a[1] * (float)b[1];
}
#endif

__device__ __forceinline__ half2_t u2h(unsigned int u) {
    union { unsigned int u; half2_t h; } x; x.u = u; return x.h;
}
__device__ __forceinline__ float sigf(float x) {
    return 1.0f / (1.0f + __expf(-x));
}
__device__ __forceinline__ float tanh_fast(float x) {
    return 1.0f - 2.0f / (__expf(2.0f * x) + 1.0f);
}

// ---- pack f32 [4*K4][1024] -> f16 blocks [(k4,j2)] of 8 halfs:
// halfs 0..3 = rows 4k4..4k4+3 of col 2j2; halfs 4..7 = same rows, col 2j2+1.
__global__ void __launch_bounds__(256)
pack_f16(const float* __restrict__ src, unsigned int* __restrict__ dst, int K4)
{
    int idx = blockIdx.x * 256 + threadIdx.x;       // over K4*512
    if (idx >= K4 * 512) return;
    const int k4 = idx >> 9, j2 = idx & 511;
    const float* s = src + (size_t)(4 * k4) * G4 + 2 * j2;
    auto pk = [](float a, float b) {
        union { _Float16 h[2]; unsigned int u; } x;
        x.h[0] = (_Float16)a; x.h[1] = (_Float16)b; return x.u;
    };
    uint4 o;
    o.x = pk(s[0 * G4 + 0], s[1 * G4 + 0]);
    o.y = pk(s[2 * G4 + 0], s[3 * G4 + 0]);
    o.z = pk(s[0 * G4 + 1], s[1 * G4 + 1]);
    o.w = pk(s[2 * G4 + 1], s[3 * G4 + 1]);
    reinterpret_cast<uint4*>(dst)[idx] = o;
}

extern "C" __global__ void __launch_bounds__(1024)
lstm_f16(const float* __restrict__ X, const uint4* __restrict__ Upk,
         const uint4* __restrict__ Wpk, const float* __restrict__ bias,
         const float* __restrict__ h0, const float* __restrict__ c0,
         float* __restrict__ out)
{
    __shared__ float xw[TC][G4];                    // 64 KB
    __shared__ __align__(16) unsigned int Xs[TC][DD / 2];  // 4 KB (f16x2)
    __shared__ float gvp[2][G4];                    // 8 KB partial gates
    __shared__ __align__(8) unsigned short hpk[HH]; // 0.5 KB h as f16

    const int b = blockIdx.x;
    const int tid = threadIdx.x;
    const int kg = tid >> 9;        // K-group 0/1
    const int j2 = tid & 511;       // column pair: cols 2j2, 2j2+1

    float c_reg = 0.0f, h_last = 0.0f;
    if (tid < HH) {
        const float hv = h0[b * HH + tid];
        union { _Float16 h; unsigned short u; } cv; cv.h = (_Float16)hv;
        hpk[tid] = cv.u;
        c_reg = c0[b * HH + tid];
        h_last = hv;
    }
    const float2 bs = reinterpret_cast<const float2*>(bias)[j2];
    __syncthreads();

    for (int chunk = 0; chunk < TT / TC; ++chunk) {
        const int t0 = chunk * TC;

        // ---- stage X chunk as packed f16x2: Xs[t][k2] = {X[t][2k2],X[t][2k2+1]}
        {
            const float2* src = reinterpret_cast<const float2*>(X + ((size_t)b * TT + t0) * DD);
            const float2 v = src[tid];              // 1024 items, 1/thread
            union { _Float16 h[2]; unsigned int u; } x;
            x.h[0] = (_Float16)v.x; x.h[1] = (_Float16)v.y;
            Xs[tid >> 6][tid & 63] = x.u;
        }
        __syncthreads();

        // ---- xw = X@W + bias; each thread: 8 timesteps (by kg) x 2 cols, full D
        {
            float a0[8], a1[8];
            #pragma unroll
            for (int t = 0; t < 8; ++t) { a0[t] = bs.x; a1[t] = bs.y; }
            #pragma unroll 8
            for (int k4 = 0; k4 < DD / 4; ++k4) {
                const uint4 wp = Wpk[(size_t)k4 * 512 + j2];
                #pragma unroll
                for (int t = 0; t < 8; ++t) {
                    const uint2 xp = *reinterpret_cast<const uint2*>(&Xs[kg * 8 + t][2 * k4]);
                    a0[t] = FDOT2(u2h(xp.x), u2h(wp.x), a0[t]);
                    a0[t] = FDOT2(u2h(xp.y), u2h(wp.y), a0[t]);
                    a1[t] = FDOT2(u2h(xp.x), u2h(wp.z), a1[t]);
                    a1[t] = FDOT2(u2h(xp.y), u2h(wp.w), a1[t]);
                }
            }
            #pragma unroll
            for (int t = 0; t < 8; ++t)
                *reinterpret_cast<float2*>(&xw[kg * 8 + t][2 * j2]) = make_float2(a0[t], a1[t]);
        }
        __syncthreads();

        // ---- TC recurrent steps
        for (int t = 0; t < TC; ++t) {
            float a0, a1;
            if (kg == 0) {
                const float2 x2 = *reinterpret_cast<const float2*>(&xw[t][2 * j2]);
                a0 = x2.x; a1 = x2.y;
            } else { a0 = 0.0f; a1 = 0.0f; }
            #pragma unroll
            for (int k4 = 0; k4 < 32; ++k4) {       // 128 rows per group
                const int gk4 = kg * 32 + k4;
                const uint4 up = Upk[(size_t)gk4 * 512 + j2];
                const uint2 hp = *reinterpret_cast<const uint2*>(&hpk[4 * gk4]);
                a0 = FDOT2(u2h(hp.x), u2h(up.x), a0);
                a0 = FDOT2(u2h(hp.y), u2h(up.y), a0);
                a1 = FDOT2(u2h(hp.x), u2h(up.z), a1);
                a1 = FDOT2(u2h(hp.y), u2h(up.w), a1);
            }
            *reinterpret_cast<float2*>(&gvp[kg][2 * j2]) = make_float2(a0, a1);
            __syncthreads();
            if (tid < HH) {
                const float gi = gvp[0][tid] + gvp[1][tid];
                const float gf = gvp[0][tid + HH] + gvp[1][tid + HH];
                const float gg = gvp[0][tid + 2 * HH] + gvp[1][tid + 2 * HH];
                const float go = gvp[0][tid + 3 * HH] + gvp[1][tid + 3 * HH];
                const float it = sigf(gi);
                const float ft = sigf(gf);
                const float gt = tanh_fast(gg);
                const float ot = sigf(go);
                c_reg = fmaf(ft, c_reg, it * gt);
                const float hn = ot * tanh_fast(c_reg);
                h_last = hn;
                out[((size_t)b * TT + (t0 + t)) * HH + tid] = hn;
                union { _Float16 h; unsigned short u; } cv; cv.h = (_Float16)hn;
                hpk[tid] = cv.u;
            }
            __syncthreads();
        }
    }

    if (tid < HH) {
        const size_t base = (size_t)BB * TT * HH;
        out[base + (size_t)b * HH + tid] = h_last;
        out[base + (size_t)BB * HH + (size_t)b * HH + tid] = c_reg;
    }
}

// ================= R2 fallback (f32 streaming) — used if ws too small =======
__device__ __forceinline__ float sigf2(float x) { return 1.0f / (1.0f + __expf(-x)); }

extern "C" __global__ void __launch_bounds__(512)
lstm_persist(const float* __restrict__ X, const float* __restrict__ W,
             const float* __restrict__ U, const float* __restrict__ bias,
             const float* __restrict__ h0, const float* __restrict__ c0,
             float* __restrict__ out)
{
    __shared__ float xw[TC][G4];
    __shared__ float Xs[TC][DD];
    __shared__ float hsh[HH];
    __shared__ float gv[G4];

    const int b = blockIdx.x;
    const int tid = threadIdx.x;
    const float2* __restrict__ U2 = reinterpret_cast<const float2*>(U);
    const float2* __restrict__ W2 = reinterpret_cast<const float2*>(W);

    float c_reg = 0.0f;
    if (tid < HH) { hsh[tid] = h0[b * HH + tid]; c_reg = c0[b * HH + tid]; }
    const float2 bs = reinterpret_cast<const float2*>(bias)[tid];
    __syncthreads();

    for (int chunk = 0; chunk < TT / TC; ++chunk) {
        const int t0 = chunk * TC;
        {
            const float4* src = reinterpret_cast<const float4*>(X + ((size_t)b * TT + t0) * DD);
            float4* dst = reinterpret_cast<float4*>(&Xs[0][0]);
            for (int i = tid; i < TC * DD / 4; i += 512) dst[i] = src[i];
        }
        __syncthreads();
        float acc0[TC], acc1[TC];
        #pragma unroll
        for (int t = 0; t < TC; ++t) { acc0[t] = bs.x; acc1[t] = bs.y; }
        for (int kk = 0; kk < DD; kk += 4) {
            const float2 w0 = W2[(size_t)(kk + 0) * (G4 / 2) + tid];
            const float2 w1 = W2[(size_t)(kk + 1) * (G4 / 2) + tid];
            const float2 w2 = W2[(size_t)(kk + 2) * (G4 / 2) + tid];
            const float2 w3 = W2[(size_t)(kk + 3) * (G4 / 2) + tid];
            #pragma unroll
            for (int t = 0; t < TC; ++t) {
                const float4 xv = *reinterpret_cast<const float4*>(&Xs[t][kk]);
                acc0[t] = fmaf(xv.x, w0.x, acc0[t]); acc1[t] = fmaf(xv.x, w0.y, acc1[t]);
                acc0[t] = fmaf(xv.y, w1.x, acc0[t]); acc1[t] = fmaf(xv.y, w1.y, acc1[t]);
                acc0[t] = fmaf(xv.z, w2.x, acc0[t]); acc1[t] = fmaf(xv.z, w2.y, acc1[t]);
                acc0[t] = fmaf(xv.w, w3.x, acc0[t]); acc1[t] = fmaf(xv.w, w3.y, acc1[t]);
            }
        }
        #pragma unroll
        for (int t = 0; t < TC; ++t)
            *reinterpret_cast<float2*>(&xw[t][2 * tid]) = make_float2(acc0[t], acc1[t]);
        __syncthreads();

        for (int t = 0; t < TC; ++t) {
            const float2 x2 = *reinterpret_cast<const float2*>(&xw[t][2 * tid]);
            float a0 = x2.x, a1 = x2.y;
            #pragma unroll 4
            for (int k = 0; k < HH; k += 4) {
                const float4 hk = *reinterpret_cast<const float4*>(&hsh[k]);
                const float2 u0 = U2[(size_t)(k + 0) * (G4 / 2) + tid];
                const float2 u1 = U2[(size_t)(k + 1) * (G4 / 2) + tid];
                const float2 u2 = U2[(size_t)(k + 2) * (G4 / 2) + tid];
                const float2 u3 = U2[(size_t)(k + 3) * (G4 / 2) + tid];
                a0 = fmaf(hk.x, u0.x, a0); a1 = fmaf(hk.x, u0.y, a1);
                a0 = fmaf(hk.y, u1.x, a0); a1 = fmaf(hk.y, u1.y, a1);
                a0 = fmaf(hk.z, u2.x, a0); a1 = fmaf(hk.z, u2.y, a1);
                a0 = fmaf(hk.w, u3.x, a0); a1 = fmaf(hk.w, u3.y, a1);
            }
            *reinterpret_cast<float2*>(&gv[2 * tid]) = make_float2(a0, a1);
            __syncthreads();
            if (tid < HH) {
                const float it = sigf2(gv[tid]);
                const float ft = sigf2(gv[tid + HH]);
                const float gt = tanh_fast(gv[tid + 2 * HH]);
                const float ot = sigf2(gv[tid + 3 * HH]);
                c_reg = fmaf(ft, c_reg, it * gt);
                const float hn = ot * tanh_fast(c_reg);
                hsh[tid] = hn;
                out[((size_t)b * TT + (t0 + t)) * HH + tid] = hn;
            }
            __syncthreads();
        }
    }
    if (tid < HH) {
        const size_t base = (size_t)BB * TT * HH;
        out[base + (size_t)b * HH + tid] = hsh[tid];
        out[base + (size_t)BB * HH + (size_t)b * HH + tid] = c_reg;
    }
}

extern "C" void kernel_launch(void* const* d_in, const int* in_sizes, int n_in,
                              void* d_out, int out_size, void* d_ws, size_t ws_size,
                              hipStream_t stream) {
    const float* X    = (const float*)d_in[0];
    const float* W    = (const float*)d_in[1];
    const float* U    = (const float*)d_in[2];
    const float* bias = (const float*)d_in[3];
    const float* h0   = (const float*)d_in[4];
    const float* c0   = (const float*)d_in[5];
    float* out = (float*)d_out;
    (void)in_sizes; (void)n_in; (void)out_size;

    const size_t upk_bytes = (size_t)(HH / 4) * 512 * 16;   // 512 KB
    const size_t wpk_bytes = (size_t)(DD / 4) * 512 * 16;   // 256 KB
    if (ws_size >= upk_bytes + wpk_bytes) {
        unsigned int* Upk = (unsigned int*)d_ws;
        unsigned int* Wpk = (unsigned int*)((char*)d_ws + upk_bytes);
        pack_f16<<<dim3((HH / 4) * 512 / 256), dim3(256), 0, stream>>>(U, Upk, HH / 4);
        pack_f16<<<dim3((DD / 4) * 512 / 256), dim3(256), 0, stream>>>(W, Wpk, DD / 4);
        lstm_f16<<<dim3(BB), dim3(1024), 0, stream>>>(
            X, (const uint4*)Upk, (const uint4*)Wpk, bias, h0, c0, out);
    } else {
        lstm_persist<<<dim3(BB), dim3(512), 0, stream>>>(X, W, U, bias, h0, c0, out);
    }
}